// Round 1
// baseline (77.853 us; speedup 1.0000x reference)
//
#include <hip/hip_runtime.h>

#define BATCH 4
#define TLEN 4096
#define DMODEL 1024
#define DHEAD 128
#define CHUNK 128
#define NCHUNK 32

typedef __attribute__((ext_vector_type(4))) float f32x4;
typedef __attribute__((ext_vector_type(8))) short bf16x8;

__device__ __forceinline__ unsigned short f2bf(float f) {
  union { float f; unsigned u; } v; v.f = f;
  unsigned r = v.u + 0x7FFF + ((v.u >> 16) & 1);   // RNE
  return (unsigned short)(r >> 16);
}
__device__ __forceinline__ float bf2f(unsigned short h) {
  union { unsigned u; float f; } v; v.u = ((unsigned)h) << 16;
  return v.f;
}

// ---------------- K0: W -> W^T bf16 [which][n][k] ----------------
__global__ __launch_bounds__(256) void transpose_w_kernel(
    const float* __restrict__ Wq, const float* __restrict__ Wk,
    const float* __restrict__ Wv, unsigned short* __restrict__ WT) {
  int id = blockIdx.x * 256 + threadIdx.x;          // 0 .. 3*131072-1
  int w = id >> 17;
  int rem = id & 131071;
  int n = rem >> 10;
  int k = rem & 1023;
  const float* W = (w == 0) ? Wq : (w == 1) ? Wk : Wv;
  WT[id] = f2bf(W[(size_t)k * DHEAD + n]);
}

// ---------------- K1: fused projection GEMM + phi ----------------
// grid (128, 3): blockIdx.y selects {q,k,v}. 128x128 tile, BK=32.
__global__ __launch_bounds__(256) void proj_kernel(
    const float* __restrict__ x, const unsigned short* __restrict__ WT,
    unsigned short* __restrict__ phiQ, unsigned short* __restrict__ phiK,
    unsigned short* __restrict__ Vb) {
  const int which = blockIdx.y;
  const unsigned short* Wt = WT + (size_t)which * 131072;   // [n][k]
  unsigned short* outp = (which == 0) ? phiQ : (which == 1) ? phiK : Vb;
  const int m0 = blockIdx.x * 128;
  __shared__ unsigned short xs[128][40];   // row stride 80B (16B-aligned), ~2-way banks
  __shared__ unsigned short wt[128][40];
  const int tid = threadIdx.x;
  const int wave = tid >> 6, lane = tid & 63;
  const int lrow = lane & 15, kgrp = lane >> 4;

  f32x4 acc[2][8];
#pragma unroll
  for (int i = 0; i < 2; ++i)
#pragma unroll
    for (int j = 0; j < 8; ++j) acc[i][j] = (f32x4)0.0f;

  for (int kk = 0; kk < DMODEL; kk += 32) {
    __syncthreads();
    // stage x tile 128x32 fp32 -> bf16
#pragma unroll
    for (int it = 0; it < 4; ++it) {
      int idx = it * 256 + tid;            // float4 units, 1024 total
      int r = idx >> 3;
      int c = (idx & 7) << 2;
      float4 v4 = *reinterpret_cast<const float4*>(&x[(size_t)(m0 + r) * DMODEL + kk + c]);
      ushort4 s4;
      s4.x = f2bf(v4.x); s4.y = f2bf(v4.y); s4.z = f2bf(v4.z); s4.w = f2bf(v4.w);
      *reinterpret_cast<ushort4*>(&xs[r][c]) = s4;
    }
    // stage W^T tile 128x32 bf16 (plain copy)
#pragma unroll
    for (int it = 0; it < 2; ++it) {
      int idx = it * 256 + tid;            // 8-elem units, 512 total
      int n = idx >> 2;
      int c = (idx & 3) << 3;
      uint4 v4 = *reinterpret_cast<const uint4*>(&Wt[(size_t)n * DMODEL + kk + c]);
      *reinterpret_cast<uint4*>(&wt[n][c]) = v4;
    }
    __syncthreads();

    bf16x8 afrag[2];
#pragma unroll
    for (int tr = 0; tr < 2; ++tr)
      afrag[tr] = *reinterpret_cast<const bf16x8*>(&xs[wave * 32 + tr * 16 + lrow][kgrp * 8]);
#pragma unroll
    for (int tc = 0; tc < 8; ++tc) {
      bf16x8 bfrag = *reinterpret_cast<const bf16x8*>(&wt[tc * 16 + lrow][kgrp * 8]);
      acc[0][tc] = __builtin_amdgcn_mfma_f32_16x16x32_bf16(afrag[0], bfrag, acc[0][tc], 0, 0, 0);
      acc[1][tc] = __builtin_amdgcn_mfma_f32_16x16x32_bf16(afrag[1], bfrag, acc[1][tc], 0, 0, 0);
    }
  }
  // epilogue: phi for q/k, plain for v; store bf16
#pragma unroll
  for (int tr = 0; tr < 2; ++tr)
#pragma unroll
    for (int tc = 0; tc < 8; ++tc)
#pragma unroll
      for (int r = 0; r < 4; ++r) {
        int row = m0 + wave * 32 + tr * 16 + kgrp * 4 + r;
        int coln = tc * 16 + lrow;
        float v = acc[tr][tc][r];
        if (which < 2) v = (v > 0.0f) ? (v + 1.0f) : __expf(v);
        outp[(size_t)row * DHEAD + coln] = f2bf(v);
      }
}

// ---------------- K2: per-chunk KV^T = v^T @ k, ks colsums ----------------
__global__ __launch_bounds__(256) void chunkkv_kernel(
    const unsigned short* __restrict__ phiK, const unsigned short* __restrict__ Vb,
    float* __restrict__ KVc, float* __restrict__ ksc) {
  const size_t base = (size_t)blockIdx.x * CHUNK * DHEAD;   // [b*T + c*128][128]
  __shared__ unsigned short kt[128][136];   // k^T [d][t]
  __shared__ unsigned short vt[128][136];   // v^T [dv][t]
  const int tid = threadIdx.x;
  const int wave = tid >> 6, lane = tid & 63;
  const int lrow = lane & 15, kgrp = lane >> 4;

#pragma unroll
  for (int it = 0; it < 8; ++it) {
    int idx = it * 256 + tid;
    int t = idx >> 4;
    int d0 = (idx & 15) << 3;
    uint4 k4 = *reinterpret_cast<const uint4*>(&phiK[base + (size_t)t * DHEAD + d0]);
    uint4 v4 = *reinterpret_cast<const uint4*>(&Vb[base + (size_t)t * DHEAD + d0]);
    const unsigned short* ks_ = reinterpret_cast<const unsigned short*>(&k4);
    const unsigned short* vs_ = reinterpret_cast<const unsigned short*>(&v4);
#pragma unroll
    for (int j = 0; j < 8; ++j) { kt[d0 + j][t] = ks_[j]; vt[d0 + j][t] = vs_[j]; }
  }
  __syncthreads();

  f32x4 acc[2][8];
#pragma unroll
  for (int i = 0; i < 2; ++i)
#pragma unroll
    for (int j = 0; j < 8; ++j) acc[i][j] = (f32x4)0.0f;
#pragma unroll
  for (int ks = 0; ks < 4; ++ks) {
    int t0 = ks * 32 + kgrp * 8;
    bf16x8 afrag[2];
#pragma unroll
    for (int tr = 0; tr < 2; ++tr)
      afrag[tr] = *reinterpret_cast<const bf16x8*>(&vt[wave * 32 + tr * 16 + lrow][t0]);
#pragma unroll
    for (int tc = 0; tc < 8; ++tc) {
      bf16x8 bfrag = *reinterpret_cast<const bf16x8*>(&kt[tc * 16 + lrow][t0]);
      acc[0][tc] = __builtin_amdgcn_mfma_f32_16x16x32_bf16(afrag[0], bfrag, acc[0][tc], 0, 0, 0);
      acc[1][tc] = __builtin_amdgcn_mfma_f32_16x16x32_bf16(afrag[1], bfrag, acc[1][tc], 0, 0, 0);
    }
  }
  float* KVout = KVc + (size_t)blockIdx.x * (DHEAD * DHEAD);   // [dv][d]
#pragma unroll
  for (int tr = 0; tr < 2; ++tr)
#pragma unroll
    for (int tc = 0; tc < 8; ++tc)
#pragma unroll
      for (int r = 0; r < 4; ++r) {
        int dv = wave * 32 + tr * 16 + kgrp * 4 + r;
        int d = tc * 16 + lrow;
        KVout[dv * DHEAD + d] = acc[tr][tc][r];
      }
  if (tid < 128) {
    float s = 0.0f;
    for (int t = 0; t < 128; ++t) s += bf2f(kt[tid][t]);
    ksc[(size_t)blockIdx.x * DHEAD + tid] = s;
  }
}

// ---------------- K3: exclusive prefix over chunks ----------------
__global__ __launch_bounds__(256) void prefix_kernel(
    const float* __restrict__ KVc, const float* __restrict__ ksc,
    unsigned short* __restrict__ KVp, float* __restrict__ ksp) {
  if (blockIdx.x < 256) {
    int id = blockIdx.x * 256 + threadIdx.x;   // 0..65535 = B * 128*128
    int b = id >> 14;
    int e = id & 16383;
    size_t base = (size_t)b * NCHUNK * 16384 + e;
    float acc = 0.0f;
    for (int c = 0; c < NCHUNK; ++c) {
      KVp[base + (size_t)c * 16384] = f2bf(acc);
      acc += KVc[base + (size_t)c * 16384];
    }
  } else {
    for (int i = threadIdx.x; i < 512; i += 256) {
      int b = i >> 7, d = i & 127;
      size_t base = (size_t)b * NCHUNK * DHEAD + d;
      float acc = 0.0f;
      for (int c = 0; c < NCHUNK; ++c) {
        ksp[base + (size_t)c * DHEAD] = acc;
        acc += ksc[base + (size_t)c * DHEAD];
      }
    }
  }
}

// ---------------- K4: per-chunk output ----------------
__global__ __launch_bounds__(256) void out_kernel(
    const unsigned short* __restrict__ phiQ, const unsigned short* __restrict__ phiK,
    const unsigned short* __restrict__ Vb, const unsigned short* __restrict__ KVp,
    const float* __restrict__ ksp, float* __restrict__ outp) {
  const size_t base = (size_t)blockIdx.x * CHUNK * DHEAD;
  __shared__ unsigned short qb[128][136];   // q row-major
  __shared__ unsigned short kb[128][136];   // k row-major, later P
  __shared__ unsigned short vb[128][136];   // v^T, later KV^T
  __shared__ float den_l[128];
  __shared__ float ks_l[128];
  const int tid = threadIdx.x;
  const int wave = tid >> 6, lane = tid & 63;
  const int lrow = lane & 15, kgrp = lane >> 4;

#pragma unroll
  for (int it = 0; it < 8; ++it) {
    int idx = it * 256 + tid;
    int t = idx >> 4;
    int d0 = (idx & 15) << 3;
    uint4 q4 = *reinterpret_cast<const uint4*>(&phiQ[base + (size_t)t * DHEAD + d0]);
    uint4 k4 = *reinterpret_cast<const uint4*>(&phiK[base + (size_t)t * DHEAD + d0]);
    uint4 v4 = *reinterpret_cast<const uint4*>(&Vb[base + (size_t)t * DHEAD + d0]);
    *reinterpret_cast<uint4*>(&qb[t][d0]) = q4;
    *reinterpret_cast<uint4*>(&kb[t][d0]) = k4;
    const unsigned short* vs_ = reinterpret_cast<const unsigned short*>(&v4);
#pragma unroll
    for (int j = 0; j < 8; ++j) vb[d0 + j][t] = vs_[j];
  }
  if (tid < 128) ks_l[tid] = ksp[(size_t)blockIdx.x * DHEAD + tid];
  __syncthreads();

  // S = q @ k^T   (contraction over d)
  f32x4 acc[2][8];
#pragma unroll
  for (int i = 0; i < 2; ++i)
#pragma unroll
    for (int j = 0; j < 8; ++j) acc[i][j] = (f32x4)0.0f;
#pragma unroll
  for (int ks = 0; ks < 4; ++ks) {
    int d0 = ks * 32 + kgrp * 8;
    bf16x8 afrag[2];
#pragma unroll
    for (int tr = 0; tr < 2; ++tr)
      afrag[tr] = *reinterpret_cast<const bf16x8*>(&qb[wave * 32 + tr * 16 + lrow][d0]);
#pragma unroll
    for (int tc = 0; tc < 8; ++tc) {
      bf16x8 bfrag = *reinterpret_cast<const bf16x8*>(&kb[tc * 16 + lrow][d0]);
      acc[0][tc] = __builtin_amdgcn_mfma_f32_16x16x32_bf16(afrag[0], bfrag, acc[0][tc], 0, 0, 0);
      acc[1][tc] = __builtin_amdgcn_mfma_f32_16x16x32_bf16(afrag[1], bfrag, acc[1][tc], 0, 0, 0);
    }
  }
  __syncthreads();   // everyone done reading kb as k
  // mask + write P (bf16) over kb
#pragma unroll
  for (int tr = 0; tr < 2; ++tr)
#pragma unroll
    for (int tc = 0; tc < 8; ++tc)
#pragma unroll
      for (int r = 0; r < 4; ++r) {
        int t = wave * 32 + tr * 16 + kgrp * 4 + r;
        int s = tc * 16 + lrow;
        float v = (s <= t) ? acc[tr][tc][r] : 0.0f;
        kb[t][s] = f2bf(v);
      }
  __syncthreads();   // P visible
  // den = rowsum(P) + q . ks_prefix
  if (tid < 128) {
    float s1 = 0.0f, s2 = 0.0f;
    for (int j = 0; j < 128; ++j) s1 += bf2f(kb[tid][j]);
    for (int j = 0; j < 128; ++j) s2 += bf2f(qb[tid][j]) * ks_l[j];
    den_l[tid] = s1 + s2;
  }
  // O = P @ v   (vb = v^T)
#pragma unroll
  for (int i = 0; i < 2; ++i)
#pragma unroll
    for (int j = 0; j < 8; ++j) acc[i][j] = (f32x4)0.0f;
#pragma unroll
  for (int ks = 0; ks < 4; ++ks) {
    int t0 = ks * 32 + kgrp * 8;
    bf16x8 afrag[2];
#pragma unroll
    for (int tr = 0; tr < 2; ++tr)
      afrag[tr] = *reinterpret_cast<const bf16x8*>(&kb[wave * 32 + tr * 16 + lrow][t0]);
#pragma unroll
    for (int tc = 0; tc < 8; ++tc) {
      bf16x8 bfrag = *reinterpret_cast<const bf16x8*>(&vb[tc * 16 + lrow][t0]);
      acc[0][tc] = __builtin_amdgcn_mfma_f32_16x16x32_bf16(afrag[0], bfrag, acc[0][tc], 0, 0, 0);
      acc[1][tc] = __builtin_amdgcn_mfma_f32_16x16x32_bf16(afrag[1], bfrag, acc[1][tc], 0, 0, 0);
    }
  }
  __syncthreads();   // done reading vb as v^T
  // restage KV^T (exclusive prefix, stored [dv][d]) into vb
#pragma unroll
  for (int it = 0; it < 8; ++it) {
    int idx = it * 256 + tid;
    int dv = idx >> 4;
    int d0 = (idx & 15) << 3;
    uint4 c4 = *reinterpret_cast<const uint4*>(&KVp[(size_t)blockIdx.x * 16384 + (size_t)dv * DHEAD + d0]);
    *reinterpret_cast<uint4*>(&vb[dv][d0]) = c4;
  }
  __syncthreads();
  // O += q @ KV   (B[kk=d][col=dv] = KV[d][dv] = vb[dv][d])
#pragma unroll
  for (int ks = 0; ks < 4; ++ks) {
    int d0 = ks * 32 + kgrp * 8;
    bf16x8 afrag[2];
#pragma unroll
    for (int tr = 0; tr < 2; ++tr)
      afrag[tr] = *reinterpret_cast<const bf16x8*>(&qb[wave * 32 + tr * 16 + lrow][d0]);
#pragma unroll
    for (int tc = 0; tc < 8; ++tc) {
      bf16x8 bfrag = *reinterpret_cast<const bf16x8*>(&vb[tc * 16 + lrow][d0]);
      acc[0][tc] = __builtin_amdgcn_mfma_f32_16x16x32_bf16(afrag[0], bfrag, acc[0][tc], 0, 0, 0);
      acc[1][tc] = __builtin_amdgcn_mfma_f32_16x16x32_bf16(afrag[1], bfrag, acc[1][tc], 0, 0, 0);
    }
  }
  // divide + store (den_l written before the restage barrier -> visible)
#pragma unroll
  for (int tr = 0; tr < 2; ++tr)
#pragma unroll
    for (int tc = 0; tc < 8; ++tc)
#pragma unroll
      for (int r = 0; r < 4; ++r) {
        int t = wave * 32 + tr * 16 + kgrp * 4 + r;
        int dv = tc * 16 + lrow;
        outp[base + (size_t)t * DHEAD + dv] = acc[tr][tc][r] / den_l[t];
      }
}

extern "C" void kernel_launch(void* const* d_in, const int* in_sizes, int n_in,
                              void* d_out, int out_size, void* d_ws, size_t ws_size,
                              hipStream_t stream) {
  const float* x  = (const float*)d_in[0];
  const float* Wq = (const float*)d_in[1];
  const float* Wk = (const float*)d_in[2];
  const float* Wv = (const float*)d_in[3];
  float* out = (float*)d_out;
  char* ws = (char*)d_ws;
  unsigned short* phiQ = (unsigned short*)(ws + 0);          // 4 MB
  unsigned short* phiK = (unsigned short*)(ws + 4194304);    // 4 MB
  unsigned short* Vb   = (unsigned short*)(ws + 8388608);    // 4 MB
  unsigned short* WT   = (unsigned short*)(ws + 12582912);   // 768 KB
  float*          KVc  = (float*)(ws + 13369344);            // 8 MB
  unsigned short* KVp  = (unsigned short*)(ws + 21757952);   // 4 MB
  float*          ksc  = (float*)(ws + 25952256);            // 64 KB
  float*          ksp  = (float*)(ws + 26017792);            // 64 KB

  transpose_w_kernel<<<1536, 256, 0, stream>>>(Wq, Wk, Wv, WT);
  proj_kernel<<<dim3(128, 3), 256, 0, stream>>>(x, WT, phiQ, phiK, Vb);
  chunkkv_kernel<<<128, 256, 0, stream>>>(phiK, Vb, KVc, ksc);
  prefix_kernel<<<257, 256, 0, stream>>>(KVc, ksc, KVp, ksp);
  out_kernel<<<128, 256, 0, stream>>>(phiQ, phiK, Vb, KVp, ksp, out);
}

// Round 7
// 65.187 us; speedup vs baseline: 1.1943x; 1.1943x over previous
//
#include <hip/hip_runtime.h>

#define DMODEL 1024
#define DHEAD 128
#define CHUNK 128
#define NCHUNK 32

typedef __attribute__((ext_vector_type(4))) float f32x4;
typedef __attribute__((ext_vector_type(8))) short bf16x8;

__device__ __forceinline__ unsigned short f2bf(float f) {
  union { float f; unsigned u; } v; v.f = f;
  unsigned r = v.u + 0x7FFF + ((v.u >> 16) & 1);   // RNE
  return (unsigned short)(r >> 16);
}
__device__ __forceinline__ float bf2f(unsigned short h) {
  union { unsigned u; float f; } v; v.u = ((unsigned)h) << 16;
  return v.f;
}
__device__ __forceinline__ unsigned cvtpk(float lo, float hi) {
  unsigned r;
  asm("v_cvt_pk_bf16_f32 %0, %1, %2" : "=v"(r) : "v"(lo), "v"(hi));
  return r;
}
__device__ __forceinline__ void gload16(const void* g, void* l) {
  __builtin_amdgcn_global_load_lds(
      (const __attribute__((address_space(1))) unsigned int*)g,
      (__attribute__((address_space(3))) unsigned int*)l, 16, 0, 0);
}

// ---------------- K0: W -> W^T bf16 [which][n][k] ----------------
__global__ __launch_bounds__(256) void transpose_w_kernel(
    const float* __restrict__ Wq, const float* __restrict__ Wk,
    const float* __restrict__ Wv, unsigned short* __restrict__ WT) {
  int id = blockIdx.x * 256 + threadIdx.x;          // 0 .. 3*131072-1
  int w = id >> 17;
  int rem = id & 131071;
  int n = rem >> 10;
  int k = rem & 1023;
  const float* W = (w == 0) ? Wq : (w == 1) ? Wk : Wv;
  WT[id] = f2bf(W[(size_t)k * DHEAD + n]);
}

// ---------------- K1: fused projection GEMM + phi ----------------
// grid (256, 3): BM=64, BN=128, BK=64, 128 threads (2 waves, row-split).
__global__ __launch_bounds__(128) void proj_kernel(
    const float* __restrict__ x, const unsigned short* __restrict__ WT,
    unsigned short* __restrict__ phiQ, unsigned short* __restrict__ phiK,
    unsigned short* __restrict__ Vb) {
  const int which = blockIdx.y;
  const unsigned short* Wt = WT + (size_t)which * (DHEAD * DMODEL);   // [n][k]
  unsigned short* outp = (which == 0) ? phiQ : (which == 1) ? phiK : Vb;
  const int m0 = blockIdx.x * 64;

  __shared__ float xs[64][64];             // 16 KB, 256B rows = 16 slots, swizzled
  __shared__ unsigned short ws[128][64];   // 16 KB, 128B rows = 8 slots, swizzled

  const int tid = threadIdx.x;
  const int wave = tid >> 6;               // 0..1
  const int lane = tid & 63;
  const int lrow = lane & 15, kgrp = lane >> 4;

  f32x4 acc[2][8];
#pragma unroll
  for (int i = 0; i < 2; ++i)
#pragma unroll
    for (int j = 0; j < 8; ++j) acc[i][j] = (f32x4)0.0f;

  for (int kk = 0; kk < DMODEL; kk += 64) {
    if (kk) __syncthreads();               // prior reads of LDS done
    // stage x tile 64x64 fp32 via global_load_lds, source pre-swizzled
#pragma unroll
    for (int i = 0; i < 8; ++i) {
      int instr = i * 2 + wave;
      int row = instr * 4 + (lane >> 4);
      int slot = lane & 15;
      int gcol = (slot ^ (row & 7)) << 2;
      gload16(&x[(size_t)(m0 + row) * DMODEL + kk + gcol],
              (char*)xs + instr * 1024);
    }
    // stage W^T tile 128x64 bf16
#pragma unroll
    for (int i = 0; i < 8; ++i) {
      int instr = i * 2 + wave;
      int row = instr * 8 + (lane >> 3);
      int slot = lane & 7;
      int gcol = (slot ^ (row & 7)) << 3;
      gload16(&Wt[(size_t)row * DMODEL + kk + gcol],
              (char*)ws + instr * 1024);
    }
    __syncthreads();                       // vmcnt(0) drain -> tiles ready

#pragma unroll
    for (int ks2 = 0; ks2 < 2; ++ks2) {
      bf16x8 af[2];
#pragma unroll
      for (int mr = 0; mr < 2; ++mr) {
        int arow = wave * 32 + mr * 16 + lrow;
        int s0 = ks2 * 8 + kgrp * 2;
        const float4 f0 = *reinterpret_cast<const float4*>(
            &xs[arow][(s0 ^ (arow & 7)) << 2]);
        const float4 f1 = *reinterpret_cast<const float4*>(
            &xs[arow][((s0 + 1) ^ (arow & 7)) << 2]);
        union { unsigned u[4]; bf16x8 v; } p;
        p.u[0] = cvtpk(f0.x, f0.y);
        p.u[1] = cvtpk(f0.z, f0.w);
        p.u[2] = cvtpk(f1.x, f1.y);
        p.u[3] = cvtpk(f1.z, f1.w);
        af[mr] = p.v;
      }
#pragma unroll
      for (int nr = 0; nr < 8; ++nr) {
        int brow = nr * 16 + lrow;
        int bs = ks2 * 4 + kgrp;
        bf16x8 bf = *reinterpret_cast<const bf16x8*>(
            &ws[brow][(bs ^ (brow & 7)) << 3]);
        acc[0][nr] = __builtin_amdgcn_mfma_f32_16x16x32_bf16(af[0], bf, acc[0][nr], 0, 0, 0);
        acc[1][nr] = __builtin_amdgcn_mfma_f32_16x16x32_bf16(af[1], bf, acc[1][nr], 0, 0, 0);
      }
    }
  }
  // epilogue: phi for q/k, plain for v; store bf16
#pragma unroll
  for (int mr = 0; mr < 2; ++mr)
#pragma unroll
    for (int nr = 0; nr < 8; ++nr)
#pragma unroll
      for (int r = 0; r < 4; ++r) {
        int row = m0 + wave * 32 + mr * 16 + kgrp * 4 + r;
        int col = nr * 16 + lrow;
        float v = acc[mr][nr][r];
        if (which < 2) v = (v > 0.0f) ? (v + 1.0f) : __expf(v);
        outp[(size_t)row * DHEAD + col] = f2bf(v);
      }
}

// ---------------- K2: per-chunk KV^T = v^T @ k, ks colsums ----------------
__global__ __launch_bounds__(256) void chunkkv_kernel(
    const unsigned short* __restrict__ phiK, const unsigned short* __restrict__ Vb,
    float* __restrict__ KVc, float* __restrict__ ksc) {
  const size_t base = (size_t)blockIdx.x * CHUNK * DHEAD;
  __shared__ unsigned short kt[128][136];   // k^T [d][t]
  __shared__ unsigned short vt[128][136];   // v^T [dv][t]
  __shared__ float csum[2][128];
  const int tid = threadIdx.x;
  const int wave = tid >> 6, lane = tid & 63;
  const int lrow = lane & 15, kgrp = lane >> 4;

#pragma unroll
  for (int it = 0; it < 8; ++it) {
    int idx = it * 256 + tid;
    int t = idx >> 4;
    int d0 = (idx & 15) << 3;
    uint4 k4 = *reinterpret_cast<const uint4*>(&phiK[base + (size_t)t * DHEAD + d0]);
    uint4 v4 = *reinterpret_cast<const uint4*>(&Vb[base + (size_t)t * DHEAD + d0]);
    const unsigned short* ks_ = reinterpret_cast<const unsigned short*>(&k4);
    const unsigned short* vs_ = reinterpret_cast<const unsigned short*>(&v4);
#pragma unroll
    for (int j = 0; j < 8; ++j) { kt[d0 + j][t] = ks_[j]; vt[d0 + j][t] = vs_[j]; }
  }
  __syncthreads();

  f32x4 acc[2][8];
#pragma unroll
  for (int i = 0; i < 2; ++i)
#pragma unroll
    for (int j = 0; j < 8; ++j) acc[i][j] = (f32x4)0.0f;
#pragma unroll
  for (int ks = 0; ks < 4; ++ks) {
    int t0 = ks * 32 + kgrp * 8;
    bf16x8 afrag[2];
#pragma unroll
    for (int tr = 0; tr < 2; ++tr)
      afrag[tr] = *reinterpret_cast<const bf16x8*>(&vt[wave * 32 + tr * 16 + lrow][t0]);
#pragma unroll
    for (int tc = 0; tc < 8; ++tc) {
      bf16x8 bfrag = *reinterpret_cast<const bf16x8*>(&kt[tc * 16 + lrow][t0]);
      acc[0][tc] = __builtin_amdgcn_mfma_f32_16x16x32_bf16(afrag[0], bfrag, acc[0][tc], 0, 0, 0);
      acc[1][tc] = __builtin_amdgcn_mfma_f32_16x16x32_bf16(afrag[1], bfrag, acc[1][tc], 0, 0, 0);
    }
  }
  float* KVout = KVc + (size_t)blockIdx.x * (DHEAD * DHEAD);   // [dv][d]
#pragma unroll
  for (int tr = 0; tr < 2; ++tr)
#pragma unroll
    for (int tc = 0; tc < 8; ++tc)
#pragma unroll
      for (int r = 0; r < 4; ++r) {
        int dv = wave * 32 + tr * 16 + kgrp * 4 + r;
        int d = tc * 16 + lrow;
        KVout[dv * DHEAD + d] = acc[tr][tc][r];
      }
  // ks colsum split across all 256 threads
  {
    int d = tid & 127, h = tid >> 7;
    float s = 0.0f;
    for (int t = h * 64; t < h * 64 + 64; ++t) s += bf2f(kt[d][t]);
    csum[h][d] = s;
  }
  __syncthreads();
  if (tid < 128) ksc[(size_t)blockIdx.x * DHEAD + tid] = csum[0][tid] + csum[1][tid];
}

// ---------------- K3: exclusive prefix over chunks ----------------
__global__ __launch_bounds__(256) void prefix_kernel(
    const float* __restrict__ KVc, const float* __restrict__ ksc,
    unsigned short* __restrict__ KVp, float* __restrict__ ksp) {
  if (blockIdx.x < 256) {
    int id = blockIdx.x * 256 + threadIdx.x;   // 0..65535 = B * 128*128
    int b = id >> 14;
    int e = id & 16383;
    size_t base = (size_t)b * NCHUNK * 16384 + e;
    float acc = 0.0f;
    for (int c = 0; c < NCHUNK; ++c) {
      KVp[base + (size_t)c * 16384] = f2bf(acc);
      acc += KVc[base + (size_t)c * 16384];
    }
  } else {
    for (int i = threadIdx.x; i < 512; i += 256) {
      int b = i >> 7, d = i & 127;
      size_t base = (size_t)b * NCHUNK * DHEAD + d;
      float acc = 0.0f;
      for (int c = 0; c < NCHUNK; ++c) {
        ksp[base + (size_t)c * DHEAD] = acc;
        acc += ksc[base + (size_t)c * DHEAD];
      }
    }
  }
}

// ---------------- K4: per-chunk output ----------------
__global__ __launch_bounds__(256) void out_kernel(
    const unsigned short* __restrict__ phiQ, const unsigned short* __restrict__ phiK,
    const unsigned short* __restrict__ Vb, const unsigned short* __restrict__ KVp,
    const float* __restrict__ ksp, float* __restrict__ outp) {
  const size_t base = (size_t)blockIdx.x * CHUNK * DHEAD;
  __shared__ unsigned short qb[128][136];   // q row-major
  __shared__ unsigned short kb[128][136];   // k row-major, later P
  __shared__ unsigned short vb[128][136];   // v^T, later KV^T
  __shared__ float dsum[2][128];
  __shared__ float ks_l[128];
  const int tid = threadIdx.x;
  const int wave = tid >> 6, lane = tid & 63;
  const int lrow = lane & 15, kgrp = lane >> 4;

#pragma unroll
  for (int it = 0; it < 8; ++it) {
    int idx = it * 256 + tid;
    int t = idx >> 4;
    int d0 = (idx & 15) << 3;
    uint4 q4 = *reinterpret_cast<const uint4*>(&phiQ[base + (size_t)t * DHEAD + d0]);
    uint4 k4 = *reinterpret_cast<const uint4*>(&phiK[base + (size_t)t * DHEAD + d0]);
    uint4 v4 = *reinterpret_cast<const uint4*>(&Vb[base + (size_t)t * DHEAD + d0]);
    *reinterpret_cast<uint4*>(&qb[t][d0]) = q4;
    *reinterpret_cast<uint4*>(&kb[t][d0]) = k4;
    const unsigned short* vs_ = reinterpret_cast<const unsigned short*>(&v4);
#pragma unroll
    for (int j = 0; j < 8; ++j) vb[d0 + j][t] = vs_[j];
  }
  if (tid < 128) ks_l[tid] = ksp[(size_t)blockIdx.x * DHEAD + tid];
  __syncthreads();

  // S = q @ k^T
  f32x4 acc[2][8];
#pragma unroll
  for (int i = 0; i < 2; ++i)
#pragma unroll
    for (int j = 0; j < 8; ++j) acc[i][j] = (f32x4)0.0f;
#pragma unroll
  for (int ks = 0; ks < 4; ++ks) {
    int d0 = ks * 32 + kgrp * 8;
    bf16x8 afrag[2];
#pragma unroll
    for (int tr = 0; tr < 2; ++tr)
      afrag[tr] = *reinterpret_cast<const bf16x8*>(&qb[wave * 32 + tr * 16 + lrow][d0]);
#pragma unroll
    for (int tc = 0; tc < 8; ++tc) {
      bf16x8 bfrag = *reinterpret_cast<const bf16x8*>(&kb[tc * 16 + lrow][d0]);
      acc[0][tc] = __builtin_amdgcn_mfma_f32_16x16x32_bf16(afrag[0], bfrag, acc[0][tc], 0, 0, 0);
      acc[1][tc] = __builtin_amdgcn_mfma_f32_16x16x32_bf16(afrag[1], bfrag, acc[1][tc], 0, 0, 0);
    }
  }
  __syncthreads();   // done reading kb as k
  // mask + write P (bf16) over kb
#pragma unroll
  for (int tr = 0; tr < 2; ++tr)
#pragma unroll
    for (int tc = 0; tc < 8; ++tc)
#pragma unroll
      for (int r = 0; r < 4; ++r) {
        int t = wave * 32 + tr * 16 + kgrp * 4 + r;
        int s = tc * 16 + lrow;
        float v = (s <= t) ? acc[tr][tc][r] : 0.0f;
        kb[t][s] = f2bf(v);
      }
  __syncthreads();   // P visible
  // den halves = rowsum(P) + q . ks_prefix, all 256 threads
  {
    int d = tid & 127, h = tid >> 7;
    float s1 = 0.0f, s2 = 0.0f;
    for (int j = h * 64; j < h * 64 + 64; ++j) {
      s1 += bf2f(kb[d][j]);
      s2 += bf2f(qb[d][j]) * ks_l[j];
    }
    dsum[h][d] = s1 + s2;
  }
  // O = P @ v   (vb = v^T)
#pragma unroll
  for (int i = 0; i < 2; ++i)
#pragma unroll
    for (int j = 0; j < 8; ++j) acc[i][j] = (f32x4)0.0f;
#pragma unroll
  for (int ks = 0; ks < 4; ++ks) {
    int t0 = ks * 32 + kgrp * 8;
    bf16x8 afrag[2];
#pragma unroll
    for (int tr = 0; tr < 2; ++tr)
      afrag[tr] = *reinterpret_cast<const bf16x8*>(&kb[wave * 32 + tr * 16 + lrow][t0]);
#pragma unroll
    for (int tc = 0; tc < 8; ++tc) {
      bf16x8 bfrag = *reinterpret_cast<const bf16x8*>(&vb[tc * 16 + lrow][t0]);
      acc[0][tc] = __builtin_amdgcn_mfma_f32_16x16x32_bf16(afrag[0], bfrag, acc[0][tc], 0, 0, 0);
      acc[1][tc] = __builtin_amdgcn_mfma_f32_16x16x32_bf16(afrag[1], bfrag, acc[1][tc], 0, 0, 0);
    }
  }
  __syncthreads();   // done reading vb; dsum visible after this barrier
  // restage KV^T (exclusive prefix, stored [dv][d]) into vb
#pragma unroll
  for (int it = 0; it < 8; ++it) {
    int idx = it * 256 + tid;
    int dv = idx >> 4;
    int d0 = (idx & 15) << 3;
    uint4 c4 = *reinterpret_cast<const uint4*>(&KVp[(size_t)blockIdx.x * 16384 + (size_t)dv * DHEAD + d0]);
    *reinterpret_cast<uint4*>(&vb[dv][d0]) = c4;
  }
  __syncthreads();
  // O += q @ KV
#pragma unroll
  for (int ks = 0; ks < 4; ++ks) {
    int d0 = ks * 32 + kgrp * 8;
    bf16x8 afrag[2];
#pragma unroll
    for (int tr = 0; tr < 2; ++tr)
      afrag[tr] = *reinterpret_cast<const bf16x8*>(&qb[wave * 32 + tr * 16 + lrow][d0]);
#pragma unroll
    for (int tc = 0; tc < 8; ++tc) {
      bf16x8 bfrag = *reinterpret_cast<const bf16x8*>(&vb[tc * 16 + lrow][d0]);
      acc[0][tc] = __builtin_amdgcn_mfma_f32_16x16x32_bf16(afrag[0], bfrag, acc[0][tc], 0, 0, 0);
      acc[1][tc] = __builtin_amdgcn_mfma_f32_16x16x32_bf16(afrag[1], bfrag, acc[1][tc], 0, 0, 0);
    }
  }
  // divide + store
#pragma unroll
  for (int tr = 0; tr < 2; ++tr)
#pragma unroll
    for (int tc = 0; tc < 8; ++tc)
#pragma unroll
      for (int r = 0; r < 4; ++r) {
        int t = wave * 32 + tr * 16 + kgrp * 4 + r;
        int dv = tc * 16 + lrow;
        outp[base + (size_t)t * DHEAD + dv] = acc[tr][tc][r] / (dsum[0][t] + dsum[1][t]);
      }
}

extern "C" void kernel_launch(void* const* d_in, const int* in_sizes, int n_in,
                              void* d_out, int out_size, void* d_ws, size_t ws_size,
                              hipStream_t stream) {
  const float* x  = (const float*)d_in[0];
  const float* Wq = (const float*)d_in[1];
  const float* Wk = (const float*)d_in[2];
  const float* Wv = (const float*)d_in[3];
  float* out = (float*)d_out;
  char* ws = (char*)d_ws;
  unsigned short* phiQ = (unsigned short*)(ws + 0);          // 4 MB
  unsigned short* phiK = (unsigned short*)(ws + 4194304);    // 4 MB
  unsigned short* Vb   = (unsigned short*)(ws + 8388608);    // 4 MB
  unsigned short* WT   = (unsigned short*)(ws + 12582912);   // 768 KB
  float*          KVc  = (float*)(ws + 13369344);            // 8 MB
  unsigned short* KVp  = (unsigned short*)(ws + 21757952);   // 4 MB
  float*          ksc  = (float*)(ws + 25952256);            // 64 KB
  float*          ksp  = (float*)(ws + 26017792);            // 64 KB

  transpose_w_kernel<<<1536, 256, 0, stream>>>(Wq, Wk, Wv, WT);
  proj_kernel<<<dim3(256, 3), 128, 0, stream>>>(x, WT, phiQ, phiK, Vb);
  chunkkv_kernel<<<128, 256, 0, stream>>>(phiK, Vb, KVc, ksc);
  prefix_kernel<<<257, 256, 0, stream>>>(KVc, ksc, KVp, ksp);
  out_kernel<<<128, 256, 0, stream>>>(phiQ, phiK, Vb, KVp, ksp, out);
}